// Round 18
// baseline (107.349 us; speedup 1.0000x reference)
//
#include <hip/hip_runtime.h>

typedef unsigned short u16;
typedef unsigned int u32;
typedef float f32x4 __attribute__((ext_vector_type(4)));
typedef float f32x16 __attribute__((ext_vector_type(16)));
typedef unsigned int u32x4 __attribute__((ext_vector_type(4)));
typedef unsigned int u32x2 __attribute__((ext_vector_type(2)));
typedef unsigned short u16x8 __attribute__((ext_vector_type(8)));
typedef unsigned short u16x4 __attribute__((ext_vector_type(4)));

#define DEV static __device__ __forceinline__

constexpr int BB = 2, TT = 2048, CC = 1024, HH = 16, DD = 64;
constexpr int MDIM = BB * TT;  // 4096

DEV u16 f2bf(float f) {
  unsigned int u = __builtin_bit_cast(unsigned int, f);
  u += 0x7fffu + ((u >> 16) & 1u);
  return (u16)(u >> 16);
}
DEV float bf2f(u16 h) {
  unsigned int u = ((unsigned int)h) << 16;
  return __builtin_bit_cast(float, u);
}
DEV void async16(const void* g, void* l) {
  __builtin_amdgcn_global_load_lds(
      (const __attribute__((address_space(1))) unsigned int*)g,
      (__attribute__((address_space(3))) unsigned int*)l, 16, 0, 0);
}
DEV void mfma16(f32x4& acc, u32x4 a, u32x4 b) {
  asm volatile("v_mfma_f32_16x16x32_bf16 %0, %1, %2, %0"
               : "+v"(acc)
               : "v"(a), "v"(b));
}
DEV void mfma32(f32x16& acc, u32x4 a, u32x4 b) {
  asm volatile("v_mfma_f32_32x32x16_bf16 %0, %1, %2, %0"
               : "+v"(acc)
               : "v"(a), "v"(b));
}
DEV u32 cvtpk(float lo, float hi) {
  u32 r;
  asm("v_cvt_pk_bf16_f32 %0, %1, %2" : "=v"(r) : "v"(lo), "v"(hi));
  return r;
}
DEV void pswap(u32& a, u32& b) {
#if __has_builtin(__builtin_amdgcn_permlane32_swap)
  u32x2 r = __builtin_amdgcn_permlane32_swap(a, b, false, false);
  a = r.x;
  b = r.y;
#else
  asm volatile("v_permlane32_swap_b32 %0, %1" : "+v"(a), "+v"(b));
#endif
}
DEV float exp2g(float x) {
#if __has_builtin(__builtin_amdgcn_exp2f)
  return __builtin_amdgcn_exp2f(x);
#else
  return exp2f(x);
#endif
}

// ---------------------------------------------------------------- prep ----
__global__ void prep_all(const float* __restrict__ x,
                         const float* __restrict__ Wa, const float* __restrict__ Wp,
                         u16* __restrict__ x_bf,
                         u16* __restrict__ Wa_t, u16* __restrict__ Wp_t) {
  __shared__ float tile[32][33];
  int bx = blockIdx.x;
  const int tx = threadIdx.x, ty = threadIdx.y;
  if (bx >= 128) {
    const int cb = (bx - 128) * 32 + blockIdx.y;
    const int i = (cb * 1024 + ty * 32 + tx) * 4;
    f32x4 v = *(const f32x4*)(x + i);
    u16x4 o;
#pragma unroll
    for (int j = 0; j < 4; ++j) o[j] = f2bf(v[j]);
    *(u16x4*)(x_bf + i) = o;
    return;
  }
  const float* in;
  u16* out;
  int Cc;
  if (bx < 96) { in = Wa; out = Wa_t; Cc = 3072; }
  else { bx -= 96; in = Wp; out = Wp_t; Cc = 1024; }
  const int R = 1024;
  const int x0 = bx * 32, y0 = blockIdx.y * 32;
  tile[ty][tx] = in[(size_t)(y0 + ty) * Cc + (x0 + tx)];
  __syncthreads();
  out[(size_t)(x0 + ty) * R + (y0 + tx)] = f2bf(tile[tx][ty]);
}

// -------------------------------------------------- qkv GEMM (256x192) ----
// R17: BK=32, 4-deep LDS buffers (A 4x16KB @0, B 4x12KB @64KB = 112KB),
// stage distance 3 (~750cy covers L2/HBM latency), ONE barrier per iter:
//   vmcnt(2*Lw) -> barrier -> STAGE(kt+3) -> compute(kt)
// WAR safety: STAGE(kt+3) writes buf[(kt-1)&3]; its readers (compute(kt-1))
// all passed barrier(kt). Per-wave loads: A 2 chunks all waves; B 2 chunks
// w<4, 1 chunk w>=4 -> per-wave literal vmcnt (8/6, then 4/3, then 0).
// 64B-row swizzle: source slot (l&3)^((l>>2)&3); read slot g^(c16&3)
// -> 2 lanes per 4-bank group (free, m136).
__global__ __launch_bounds__(512, 2) void gemm_qkv256(
    const u16* __restrict__ A, const u16* __restrict__ Bt,
    const float* __restrict__ bias,
    u16* __restrict__ qw, u16* __restrict__ kw, u16* __restrict__ vw) {
  extern __shared__ char smem[];
  const int K = CC, NT = K / 32;  // 32 iterations
  const int tid = threadIdx.x;
  const int lane = tid & 63, w = tid >> 6;  // 8 waves
  const int g = lane >> 4, c16 = lane & 15;
  const int wm2 = (w >> 2) * 128, wn2 = (w & 3) * 48;

  const int wgid = blockIdx.x;
  const int xcd = wgid & 7, idx = wgid >> 3;
  const int patch = xcd * 2 + (idx >> 4);
  const int q = idx & 15;
  const int bys = (patch & 3) * 4 + (q & 3);
  const int bxs = (patch >> 2) * 4 + (q >> 2);
  const int brow = bys * 256, bcol = bxs * 192;

  // staging: lane l -> row c*16 + (l>>2), slot (l&3)^((l>>2)&3) (64B rows)
  const int ssw = ((lane & 3) ^ ((lane >> 2) & 3)) << 4;
  // read: slot g ^ (c16&3)
  const int rsw = (g ^ (c16 & 3)) << 4;

  f32x4 acc[8][3];
#pragma unroll
  for (int m = 0; m < 8; ++m)
#pragma unroll
    for (int n = 0; n < 3; ++n) acc[m][n] = f32x4{0.f, 0.f, 0.f, 0.f};

  const size_t ldb = (size_t)K * 2;
  const char* Abase = (const char*)A + (size_t)brow * ldb;
  const char* Bbase = (const char*)Bt + (size_t)bcol * ldb;

  // A: 16 chunks (16 rows x 64B each), 2/wave. B: 12 chunks, 2/wave w<4,
  // 1/wave w>=4.
  auto STAGE = [&](int kt) {
    const int par = kt & 3;
    char* Adst = smem + par * 16384;
    char* Bdst = smem + 65536 + par * 12288;
    const size_t koff = (size_t)kt * 64;  // 32 cols * 2B
    const int rsub = lane >> 2;           // 0..15 row within chunk
#pragma unroll
    for (int i = 0; i < 2; ++i) {
      const int c = w * 2 + i;
      const int row = c * 16 + rsub;
      async16(Abase + (size_t)row * ldb + koff + ssw, Adst + c * 1024);
    }
    if (w < 4) {
#pragma unroll
      for (int i = 0; i < 2; ++i) {
        const int c = w * 2 + i;
        const int row = c * 16 + rsub;
        async16(Bbase + (size_t)row * ldb + koff + ssw, Bdst + c * 1024);
      }
    } else {
      const int c = 8 + (w - 4);
      const int row = c * 16 + rsub;
      async16(Bbase + (size_t)row * ldb + koff + ssw, Bdst + c * 1024);
    }
  };

  STAGE(0);
  STAGE(1);
  STAGE(2);

  for (int kt = 0; kt < NT; ++kt) {
    const int par = kt & 3;
    // wait own stage(kt) retired: allowed outstanding = later stages only
    if (kt + 2 < NT) {
      if (w < 4) asm volatile("s_waitcnt vmcnt(8)" ::: "memory");
      else       asm volatile("s_waitcnt vmcnt(6)" ::: "memory");
    } else if (kt + 1 < NT) {
      if (w < 4) asm volatile("s_waitcnt vmcnt(4)" ::: "memory");
      else       asm volatile("s_waitcnt vmcnt(3)" ::: "memory");
    } else {
      asm volatile("s_waitcnt vmcnt(0)" ::: "memory");
    }
    __builtin_amdgcn_sched_barrier(0);
    __builtin_amdgcn_s_barrier();
    __builtin_amdgcn_sched_barrier(0);
    if (kt + 3 < NT) STAGE(kt + 3);  // writes buf[(kt-1)&3]: readers done

    const char* Ap = smem + par * 16384;
    const char* Bp = smem + 65536 + par * 12288;
    u32x4 af[8], bf[3];
#pragma unroll
    for (int m = 0; m < 8; ++m)
      af[m] = *(const u32x4*)(Ap + (wm2 + m * 16 + c16) * 64 + rsw);
#pragma unroll
    for (int n = 0; n < 3; ++n)
      bf[n] = *(const u32x4*)(Bp + (wn2 + n * 16 + c16) * 64 + rsw);
#pragma unroll
    for (int m = 0; m < 8; ++m)
#pragma unroll
      for (int n = 0; n < 3; ++n) mfma16(acc[m][n], af[m], bf[n]);
  }

  // ---- epilogue: stage [256][192] u16 (96KB) then 16B coalesced stores ----
  __builtin_amdgcn_s_barrier();  // all compute done before E overwrites smem
  u16* E = (u16*)smem;
#pragma unroll
  for (int n = 0; n < 3; ++n) {
    const float bv = bias[bcol + wn2 + n * 16 + c16];
#pragma unroll
    for (int m = 0; m < 8; ++m)
#pragma unroll
      for (int r = 0; r < 4; ++r)
        E[(wm2 + m * 16 + g * 4 + r) * 192 + wn2 + n * 16 + c16] =
            f2bf(acc[m][n][r] + bv);
  }
  __syncthreads();
#pragma unroll
  for (int i = 0; i < 12; ++i) {
    const int c = tid + i * 512;
    {  // row-major: q/k
      const int row = c / 24, col8 = (c % 24) * 8;
      const int colg = bcol + col8;
      if (colg < 2048) {
        const int which = colg >> 10, cc = colg & 1023, h = cc >> 6, d = cc & 63;
        const int rowg = brow + row, b = rowg >> 11, t = rowg & (TT - 1);
        u16x8 v8 = *(const u16x8*)&E[row * 192 + col8];
        u16* dst = (which == 0 ? qw : kw) + ((size_t)(b * HH + h) * TT + t) * DD + d;
        *(u16x8*)dst = v8;
      }
    }
    {  // col-major: v -> [d][t]
      const int col = c % 192, row8 = (c / 192) * 8;
      const int colg = bcol + col;
      if (colg >= 2048) {
        const int cc = colg & 1023, h = cc >> 6, d = cc & 63;
        const int rowg = brow + row8, b = rowg >> 11, t = rowg & (TT - 1);
        u16x8 v8;
#pragma unroll
        for (int j = 0; j < 8; ++j) v8[j] = E[(row8 + j) * 192 + col];
        u16* dst = vw + ((size_t)(b * HH + h) * DD + d) * TT + t;
        *(u16x8*)dst = v8;
      }
    }
  }
}

// ----------------------------------------------------------- proj GEMM ----
// R16-proven: counted-vmcnt 2-deep pipeline, 256 blocks = 1/CU.
__global__ __launch_bounds__(256, 2) void gemm_proj(
    const u16* __restrict__ A, const u16* __restrict__ Bt,
    const float* __restrict__ bias, float* __restrict__ outF,
    int M, int N, int K) {
  extern __shared__ char smem_p[];  // A: 2x16KB @0 | B: 2x16KB @32KB
  const int NT = K / 64;
  const int tid = threadIdx.x;
  const int lane = tid & 63, w = tid >> 6;
  const int g = lane >> 4, c16 = lane & 15;
  const int wm = (w >> 1) * 64, wn = (w & 1) * 64;

  const int wgid = blockIdx.y * gridDim.x + blockIdx.x;
  const int xcd = wgid & 7, pi = wgid >> 3;
  const int bxs = pi & 7;
  const int bys = 4 * xcd + (pi >> 3);
  const int brow = bys * 128, bcol = bxs * 128;

  const int lrow = lane >> 3;
  const int scol = ((lane & 7) ^ lrow) << 4;
  const int rswz = (c16 & 7) << 4;

  f32x4 acc[4][4];
#pragma unroll
  for (int m = 0; m < 4; ++m)
#pragma unroll
    for (int n = 0; n < 4; ++n) acc[m][n] = f32x4{0.f, 0.f, 0.f, 0.f};

  const size_t ldb = (size_t)K * 2;
  const char* Abase = (const char*)A + (size_t)brow * ldb;
  const char* Bbase = (const char*)Bt + (size_t)bcol * ldb;

  auto STAGE = [&](int kt) {
    const int par = kt & 1;
    char* Adst = smem_p + par * 16384;
    char* Bdst = smem_p + 32768 + par * 16384;
    const size_t koff = (size_t)kt * 128;
#pragma unroll
    for (int i = 0; i < 4; ++i) {
      const int c = w * 4 + i;
      const int row = c * 8 + lrow;
      async16(Abase + (size_t)row * ldb + koff + scol, Adst + c * 1024);
      async16(Bbase + (size_t)row * ldb + koff + scol, Bdst + c * 1024);
    }
  };

  STAGE(0);
  STAGE(1);

  for (int kt = 0; kt < NT; ++kt) {
    const int par = kt & 1;
    if (kt + 1 < NT)
      asm volatile("s_waitcnt vmcnt(8)" ::: "memory");
    else
      asm volatile("s_waitcnt vmcnt(0)" ::: "memory");
    __builtin_amdgcn_sched_barrier(0);
    __builtin_amdgcn_s_barrier();
    __builtin_amdgcn_sched_barrier(0);
    const char* Ap = smem_p + par * 16384;
    const char* Bp = smem_p + 32768 + par * 16384;
#pragma unroll
    for (int kc = 0; kc < 2; ++kc) {
      const int cb = (kc * 64 + g * 16) ^ rswz;
      u32x4 af[4], bf8[4];
#pragma unroll
      for (int m = 0; m < 4; ++m)
        af[m] = *(const u32x4*)(Ap + (wm + m * 16 + c16) * 128 + cb);
#pragma unroll
      for (int n = 0; n < 4; ++n)
        bf8[n] = *(const u32x4*)(Bp + (wn + n * 16 + c16) * 128 + cb);
#pragma unroll
      for (int m = 0; m < 4; ++m)
#pragma unroll
        for (int n = 0; n < 4; ++n) mfma16(acc[m][n], af[m], bf8[n]);
    }
    __builtin_amdgcn_sched_barrier(0);
    __builtin_amdgcn_s_barrier();
    __builtin_amdgcn_sched_barrier(0);
    if (kt + 2 < NT) STAGE(kt + 2);
  }

  float* Ef = (float*)smem_p;  // [64][128] f32 = 32KB
#pragma unroll
  for (int pass = 0; pass < 2; ++pass) {
    __syncthreads();
    if ((wm >> 6) == pass) {
#pragma unroll
      for (int n = 0; n < 4; ++n) {
        const float bv = bias[bcol + wn + n * 16 + c16];
#pragma unroll
        for (int m = 0; m < 4; ++m)
#pragma unroll
          for (int r = 0; r < 4; ++r)
            Ef[(m * 16 + g * 4 + r) * 128 + wn + n * 16 + c16] = acc[m][n][r] + bv;
      }
    }
    __syncthreads();
#pragma unroll
    for (int i = 0; i < 8; ++i) {
      const int chunk = tid + i * 256;
      const int row = chunk >> 5;
      const int c4 = (chunk & 31) * 4;
      f32x4 v4 = *(const f32x4*)&Ef[row * 128 + c4];
      *(f32x4*)&outF[(size_t)(brow + pass * 64 + row) * N + bcol + c4] = v4;
    }
  }
}

// ----------------------------------------------------------- attention ----
// R16-proven (42.0us, FETCH 12.4MB): R9 structure + XCD-bh-locality mapping.
__global__ __launch_bounds__(256) void attn_fwd(
    const u16* __restrict__ qw, const u16* __restrict__ kw,
    const u16* __restrict__ vw, u16* __restrict__ ao) {
  extern __shared__ u16 smem_a[];  // [4][64*64] K, then [4][64*64] V (64KB)
  const int tid = threadIdx.x;
  const int lane = tid & 63, w = tid >> 6;
  const int ql = lane & 31, half = lane >> 5;
  const int id = blockIdx.x;
  const int xcd = id & 7, slot = id >> 3;
  const int bhl = slot >> 4, qi = slot & 15;
  const int bh = (xcd << 2) + bhl;
  const int qb = (bhl & 2) ? (15 - qi) : qi;
  const int q0w = qb * 128 + w * 32;
  const int qg = q0w + ql;
  const int lrow = lane >> 3;
  const int scol = ((lane & 7) ^ lrow) << 4;
  const int rswz = (ql & 7) << 4;

  u32x4 qf[4];
  {
    const u16* qrow = qw + ((size_t)bh * TT + qg) * DD;
    const float qs = 0.125f * 1.44269504f;
#pragma unroll
    for (int dwin = 0; dwin < 4; ++dwin) {
      u16x8 u = *(const u16x8*)(qrow + dwin * 16 + half * 8);
      u16x8 s;
#pragma unroll
      for (int j = 0; j < 8; ++j) s[j] = f2bf(bf2f(u[j]) * qs);
      qf[dwin] = __builtin_bit_cast(u32x4, s);
    }
  }

  f32x16 o0, o1;
#pragma unroll
  for (int i = 0; i < 16; ++i) { o0[i] = 0.f; o1[i] = 0.f; }
  float l_run = 0.f;

  const char* kbase = (const char*)kw + ((size_t)bh * TT) * 128;
  const char* vbase = (const char*)vw + ((size_t)bh * DD) * (TT * 2);

  const int nt = 2 * qb + 2;  // always even

  auto kptr = [&](int b) { return (char*)(smem_a + (b & 3) * 4096); };
  auto vptr = [&](int b) { return (char*)(smem_a + 16384 + (b & 3) * 4096); };

  auto STAGE = [&](int kt_) {
    if (kt_ >= nt) return;
    const int t0_ = kt_ * 64;
#pragma unroll
    for (int i_ = 0; i_ < 2; ++i_) {
      const int chunk = w * 2 + i_;
      const int row = chunk * 8 + lrow;
      async16(kbase + (size_t)(t0_ + row) * 128 + scol, kptr(kt_) + chunk * 1024);
      async16(vbase + (size_t)row * (TT * 2) + (size_t)t0_ * 2 + scol,
              vptr(kt_) + chunk * 1024);
    }
  };

  auto QK = [&](int kt_, f32x16& sa, f32x16& sb) {
    const char* Kc = kptr(kt_);
#pragma unroll
    for (int i = 0; i < 16; ++i) { sa[i] = 0.f; sb[i] = 0.f; }
    __builtin_amdgcn_s_setprio(1);
#pragma unroll
    for (int dwin = 0; dwin < 4; ++dwin) {
      const int cb = (dwin * 32 + half * 16) ^ rswz;
      u32x4 ak0 = *(const u32x4*)(Kc + (0 + ql) * 128 + cb);
      u32x4 ak1 = *(const u32x4*)(Kc + (32 + ql) * 128 + cb);
      mfma32(sa, ak0, qf[dwin]);
      mfma32(sb, ak1, qf[dwin]);
    }
    __builtin_amdgcn_s_setprio(0);
  };

  auto FINISH = [&](int kt_, f32x16& s0, f32x16& s1) {
    const int t0 = kt_ * 64;
    if (t0 >= q0w + 32) return;
    if (t0 + 63 > q0w) {
      const int kb = t0 + 4 * half - qg;
#pragma unroll
      for (int r = 0; r < 16; ++r) {
        const int ko = (r & 3) + 8 * (r >> 2);
        if (kb + ko > 0) s0[r] = -1e30f;
        if (kb + 32 + ko > 0) s1[r] = -1e30f;
      }
    }
#pragma unroll
    for (int i = 0; i < 16; ++i) {
      s0[i] = exp2g(s0[i]);
      s1[i] = exp2g(s1[i]);
    }
    float a8[8];
#pragma unroll
    for (int i = 0; i < 8; ++i)
      a8[i] = (s0[i] + s0[i + 8]) + (s1[i] + s1[i + 8]);
    float rs = ((a8[0] + a8[1]) + (a8[2] + a8[3])) + ((a8[4] + a8[5]) + (a8[6] + a8[7]));
    rs += __shfl_xor(rs, 32, 64);
    l_run += rs;

    u32x4 pf[4];
#pragma unroll
    for (int win = 0; win < 4; ++win) {
      const int b = (win & 1) * 8;
      u32 w0, w1, w2, w3;
      if (win < 2) {
        w0 = cvtpk(s0[b + 0], s0[b + 1]); w2 = cvtpk(s0[b + 4], s0[b + 5]);
        w1 = cvtpk(s0[b + 2], s0[b + 3]); w3 = cvtpk(s0[b + 6], s0[b + 7]);
      } else {
        w0 = cvtpk(s1[b + 0], s1[b + 1]); w2 = cvtpk(s1[b + 4], s1[b + 5]);
        w1 = cvtpk(s1[b + 2], s1[b + 3]); w3 = cvtpk(s1[b + 6], s1[b + 7]);
      }
      pswap(w0, w2);
      pswap(w1, w3);
      pf[win] = u32x4{w0, w1, w2, w3};
    }
    const char* Vc = vptr(kt_);
    __builtin_amdgcn_s_setprio(1);
#pragma unroll
    for (int win = 0; win < 4; ++win) {
      const int cb = (win * 32 + half * 16) ^ rswz;
      u32x4 av0 = *(const u32x4*)(Vc + (0 + ql) * 128 + cb);
      u32x4 av1 = *(const u32x4*)(Vc + (32 + ql) * 128 + cb);
      mfma32(o0, av0, pf[win]);
      mfma32(o1, av1, pf[win]);
    }
    __builtin_amdgcn_s_setprio(0);
  };

  STAGE(0);
  STAGE(1);
  STAGE(2);
  if (nt >= 3)
    asm volatile("s_waitcnt vmcnt(8)" ::: "memory");
  else
    asm volatile("s_waitcnt vmcnt(4)" ::: "memory");
  __builtin_amdgcn_sched_barrier(0);
  __builtin_amdgcn_s_barrier();
  __builtin_amdgcn_sched_barrier(0);

  f32x16 sA0, sA1, sB0, sB1;
  QK(0, sA0, sA1);

#define BODY(KT, C0, C1, N0, N1)                                          \
  {                                                                       \
    const int kt_b = (KT);                                                \
    if (kt_b + 2 < nt)                                                    \
      asm volatile("s_waitcnt vmcnt(4)" ::: "memory");                    \
    else                                                                  \
      asm volatile("s_waitcnt vmcnt(0)" ::: "memory");                    \
    __builtin_amdgcn_sched_barrier(0);                                    \
    __builtin_amdgcn_s_barrier();                                         \
    __builtin_amdgcn_sched_barrier(0);                                    \
    STAGE(kt_b + 3);                                                      \
    if (kt_b + 1 < nt && (kt_b + 1) * 64 < q0w + 32) QK(kt_b + 1, N0, N1);\
    FINISH(kt_b, C0, C1);                                                 \
  }

  for (int kt2 = 0; kt2 < nt; kt2 += 2) {
    BODY(kt2, sA0, sA1, sB0, sB1);
    BODY(kt2 + 1, sB0, sB1, sA0, sA1);
  }
#undef BODY

  const int b = bh >> 4, h = bh & 15;
  const float inv = 1.f / l_run;
  u16* aorow = ao + ((size_t)(b * TT) + qg) * CC + h * DD;
#pragma unroll
  for (int rg = 0; rg < 4; ++rg) {
    u16x4 t0v, t1v;
#pragma unroll
    for (int j = 0; j < 4; ++j) {
      t0v[j] = f2bf(o0[rg * 4 + j] * inv);
      t1v[j] = f2bf(o1[rg * 4 + j] * inv);
    }
    *(u16x4*)(aorow + 8 * rg + 4 * half) = t0v;
    *(u16x4*)(aorow + 32 + 8 * rg + 4 * half) = t1v;
  }
}

// -------------------------------------------------------------- launch ----
extern "C" void kernel_launch(void* const* d_in, const int* in_sizes, int n_in,
                              void* d_out, int out_size, void* d_ws, size_t ws_size,
                              hipStream_t stream) {
  const float* x  = (const float*)d_in[0];
  const float* Wa = (const float*)d_in[1];
  const float* ba = (const float*)d_in[2];
  const float* Wp = (const float*)d_in[3];
  const float* bp = (const float*)d_in[4];
  float* out = (float*)d_out;

  char* ws = (char*)d_ws;
  const size_t MB = 1ull << 20;
  u16* x_bf = (u16*)(ws);            // 8 MB  [4096][1024]
  u16* ao   = (u16*)(ws);            // 8 MB  alias (x_bf dead after QKV GEMM)
  u16* Wa_t = (u16*)(ws + 8 * MB);   // 6 MB  [3072][1024]
  u16* Wp_t = (u16*)(ws + 14 * MB);  // 2 MB  [1024][1024]
  u16* q_ws = (u16*)(ws + 16 * MB);  // 8 MB  [32][2048][64]
  u16* k_ws = (u16*)(ws + 24 * MB);  // 8 MB  [32][2048][64]
  u16* v_ws = (u16*)(ws + 32 * MB);  // 8 MB  [32][64][2048]

  static bool attr_set = []() {
    hipFuncSetAttribute((const void*)gemm_qkv256,
                        hipFuncAttributeMaxDynamicSharedMemorySize, 114688);
    hipFuncSetAttribute((const void*)gemm_proj,
                        hipFuncAttributeMaxDynamicSharedMemorySize, 65536);
    hipFuncSetAttribute((const void*)attn_fwd,
                        hipFuncAttributeMaxDynamicSharedMemorySize, 65536);
    return true;
  }();
  (void)attr_set;

  hipLaunchKernelGGL(prep_all, dim3(160, 32), dim3(32, 32), 0, stream,
                     x, Wa, Wp, x_bf, Wa_t, Wp_t);
  hipLaunchKernelGGL(gemm_qkv256, dim3(256), dim3(512), 114688, stream,
                     x_bf, Wa_t, ba, q_ws, k_ws, v_ws);
  hipLaunchKernelGGL(attn_fwd, dim3(512), dim3(256), 65536, stream,
                     q_ws, k_ws, v_ws, ao);
  hipLaunchKernelGGL(gemm_proj, dim3(CC / 128, MDIM / 128), dim3(256), 65536, stream,
                     ao, Wp_t, bp, out, MDIM, CC, CC);
}

// Round 19
// 104.100 us; speedup vs baseline: 1.0312x; 1.0312x over previous
//
#include <hip/hip_runtime.h>

typedef unsigned short u16;
typedef unsigned int u32;
typedef float f32x4 __attribute__((ext_vector_type(4)));
typedef float f32x16 __attribute__((ext_vector_type(16)));
typedef unsigned int u32x4 __attribute__((ext_vector_type(4)));
typedef unsigned int u32x2 __attribute__((ext_vector_type(2)));
typedef unsigned short u16x8 __attribute__((ext_vector_type(8)));
typedef unsigned short u16x4 __attribute__((ext_vector_type(4)));

#define DEV static __device__ __forceinline__

constexpr int BB = 2, TT = 2048, CC = 1024, HH = 16, DD = 64;
constexpr int MDIM = BB * TT;  // 4096

DEV u16 f2bf(float f) {
  unsigned int u = __builtin_bit_cast(unsigned int, f);
  u += 0x7fffu + ((u >> 16) & 1u);
  return (u16)(u >> 16);
}
DEV float bf2f(u16 h) {
  unsigned int u = ((unsigned int)h) << 16;
  return __builtin_bit_cast(float, u);
}
DEV void async16(const void* g, void* l) {
  __builtin_amdgcn_global_load_lds(
      (const __attribute__((address_space(1))) unsigned int*)g,
      (__attribute__((address_space(3))) unsigned int*)l, 16, 0, 0);
}
DEV void mfma16(f32x4& acc, u32x4 a, u32x4 b) {
  asm volatile("v_mfma_f32_16x16x32_bf16 %0, %1, %2, %0"
               : "+v"(acc)
               : "v"(a), "v"(b));
}
DEV void mfma32(f32x16& acc, u32x4 a, u32x4 b) {
  asm volatile("v_mfma_f32_32x32x16_bf16 %0, %1, %2, %0"
               : "+v"(acc)
               : "v"(a), "v"(b));
}
DEV u32 cvtpk(float lo, float hi) {
  u32 r;
  asm("v_cvt_pk_bf16_f32 %0, %1, %2" : "=v"(r) : "v"(lo), "v"(hi));
  return r;
}
DEV void pswap(u32& a, u32& b) {
#if __has_builtin(__builtin_amdgcn_permlane32_swap)
  u32x2 r = __builtin_amdgcn_permlane32_swap(a, b, false, false);
  a = r.x;
  b = r.y;
#else
  asm volatile("v_permlane32_swap_b32 %0, %1" : "+v"(a), "+v"(b));
#endif
}
DEV float exp2g(float x) {
#if __has_builtin(__builtin_amdgcn_exp2f)
  return __builtin_amdgcn_exp2f(x);
#else
  return exp2f(x);
#endif
}

// ---------------------------------------------------------------- prep ----
__global__ void prep_all(const float* __restrict__ x,
                         const float* __restrict__ Wa, const float* __restrict__ Wp,
                         u16* __restrict__ x_bf,
                         u16* __restrict__ Wa_t, u16* __restrict__ Wp_t) {
  __shared__ float tile[32][33];
  int bx = blockIdx.x;
  const int tx = threadIdx.x, ty = threadIdx.y;
  if (bx >= 128) {
    const int cb = (bx - 128) * 32 + blockIdx.y;
    const int i = (cb * 1024 + ty * 32 + tx) * 4;
    f32x4 v = *(const f32x4*)(x + i);
    u16x4 o;
#pragma unroll
    for (int j = 0; j < 4; ++j) o[j] = f2bf(v[j]);
    *(u16x4*)(x_bf + i) = o;
    return;
  }
  const float* in;
  u16* out;
  int Cc;
  if (bx < 96) { in = Wa; out = Wa_t; Cc = 3072; }
  else { bx -= 96; in = Wp; out = Wp_t; Cc = 1024; }
  const int R = 1024;
  const int x0 = bx * 32, y0 = blockIdx.y * 32;
  tile[ty][tx] = in[(size_t)(y0 + ty) * Cc + (x0 + tx)];
  __syncthreads();
  out[(size_t)(x0 + ty) * R + (y0 + tx)] = f2bf(tile[tx][ty]);
}

// -------------------------------------------------- qkv GEMM (256x192) ----
// R15-proven (best: ~36us): BK=64, counted-vmcnt 2-deep pipeline, 256
// blocks = 1/CU, 8 waves. (R17's BK=32 variant regressed: more bank
// conflicts + higher relative barrier overhead at constant wave budget.)
__global__ __launch_bounds__(512, 2) void gemm_qkv256(
    const u16* __restrict__ A, const u16* __restrict__ Bt,
    const float* __restrict__ bias,
    u16* __restrict__ qw, u16* __restrict__ kw, u16* __restrict__ vw) {
  extern __shared__ char smem[];  // A: 2x32KB @0 | B: 2x24KB @64KB = 112KB
  const int K = CC, NT = K / 64;
  const int tid = threadIdx.x;
  const int lane = tid & 63, w = tid >> 6;
  const int g = lane >> 4, c16 = lane & 15;
  const int wm2 = (w >> 2) * 128, wn2 = (w & 3) * 48;

  const int wgid = blockIdx.x;
  const int xcd = wgid & 7, idx = wgid >> 3;
  const int patch = xcd * 2 + (idx >> 4);
  const int q = idx & 15;
  const int bys = (patch & 3) * 4 + (q & 3);
  const int bxs = (patch >> 2) * 4 + (q >> 2);
  const int brow = bys * 256, bcol = bxs * 192;

  const int lrow = lane >> 3;
  const int scol = ((lane & 7) ^ lrow) << 4;
  const int rswz = (c16 & 7) << 4;

  f32x4 acc[8][3];
#pragma unroll
  for (int m = 0; m < 8; ++m)
#pragma unroll
    for (int n = 0; n < 3; ++n) acc[m][n] = f32x4{0.f, 0.f, 0.f, 0.f};

  const size_t ldb = (size_t)K * 2;
  const char* Abase = (const char*)A + (size_t)brow * ldb;
  const char* Bbase = (const char*)Bt + (size_t)bcol * ldb;

  auto STAGE = [&](int kt) {
    const int par = kt & 1;
    char* Adst = smem + par * 32768;
    char* Bdst = smem + 65536 + par * 24576;
    const size_t koff = (size_t)kt * 128;
#pragma unroll
    for (int i = 0; i < 4; ++i) {
      const int c = w * 4 + i;
      const int row = c * 8 + lrow;
      async16(Abase + (size_t)row * ldb + koff + scol, Adst + c * 1024);
    }
#pragma unroll
    for (int i = 0; i < 3; ++i) {
      const int c = w * 3 + i;
      const int row = c * 8 + lrow;
      async16(Bbase + (size_t)row * ldb + koff + scol, Bdst + c * 1024);
    }
  };

  STAGE(0);
  STAGE(1);

  for (int kt = 0; kt < NT; ++kt) {
    const int par = kt & 1;
    if (kt + 1 < NT)
      asm volatile("s_waitcnt vmcnt(7)" ::: "memory");
    else
      asm volatile("s_waitcnt vmcnt(0)" ::: "memory");
    __builtin_amdgcn_sched_barrier(0);
    __builtin_amdgcn_s_barrier();
    __builtin_amdgcn_sched_barrier(0);
    const char* Ap = smem + par * 32768;
    const char* Bp = smem + 65536 + par * 24576;
#pragma unroll
    for (int kc = 0; kc < 2; ++kc) {
      const int cb = (kc * 64 + g * 16) ^ rswz;
      u32x4 af[8], bf[3];
#pragma unroll
      for (int m = 0; m < 8; ++m)
        af[m] = *(const u32x4*)(Ap + (wm2 + m * 16 + c16) * 128 + cb);
#pragma unroll
      for (int n = 0; n < 3; ++n)
        bf[n] = *(const u32x4*)(Bp + (wn2 + n * 16 + c16) * 128 + cb);
#pragma unroll
      for (int m = 0; m < 8; ++m)
#pragma unroll
        for (int n = 0; n < 3; ++n) mfma16(acc[m][n], af[m], bf[n]);
    }
    __builtin_amdgcn_sched_barrier(0);
    __builtin_amdgcn_s_barrier();
    __builtin_amdgcn_sched_barrier(0);
    if (kt + 2 < NT) STAGE(kt + 2);
  }

  u16* E = (u16*)smem;
#pragma unroll
  for (int n = 0; n < 3; ++n) {
    const float bv = bias[bcol + wn2 + n * 16 + c16];
#pragma unroll
    for (int m = 0; m < 8; ++m)
#pragma unroll
      for (int r = 0; r < 4; ++r)
        E[(wm2 + m * 16 + g * 4 + r) * 192 + wn2 + n * 16 + c16] =
            f2bf(acc[m][n][r] + bv);
  }
  __syncthreads();
#pragma unroll
  for (int i = 0; i < 12; ++i) {
    const int c = tid + i * 512;
    {  // row-major: q/k
      const int row = c / 24, col8 = (c % 24) * 8;
      const int colg = bcol + col8;
      if (colg < 2048) {
        const int which = colg >> 10, cc = colg & 1023, h = cc >> 6, d = cc & 63;
        const int rowg = brow + row, b = rowg >> 11, t = rowg & (TT - 1);
        u16x8 v8 = *(const u16x8*)&E[row * 192 + col8];
        u16* dst = (which == 0 ? qw : kw) + ((size_t)(b * HH + h) * TT + t) * DD + d;
        *(u16x8*)dst = v8;
      }
    }
    {  // col-major: v -> [d][t]
      const int col = c % 192, row8 = (c / 192) * 8;
      const int colg = bcol + col;
      if (colg >= 2048) {
        const int cc = colg & 1023, h = cc >> 6, d = cc & 63;
        const int rowg = brow + row8, b = rowg >> 11, t = rowg & (TT - 1);
        u16x8 v8;
#pragma unroll
        for (int j = 0; j < 8; ++j) v8[j] = E[(row8 + j) * 192 + col];
        u16* dst = vw + ((size_t)(b * HH + h) * DD + d) * TT + t;
        *(u16x8*)dst = v8;
      }
    }
  }
}

// ----------------------------------------------------------- proj GEMM ----
// R16-proven: counted-vmcnt 2-deep pipeline, 256 blocks = 1/CU (plus a 2nd
// resident block from the 64KB LDS budget).
__global__ __launch_bounds__(256, 2) void gemm_proj(
    const u16* __restrict__ A, const u16* __restrict__ Bt,
    const float* __restrict__ bias, float* __restrict__ outF,
    int M, int N, int K) {
  extern __shared__ char smem_p[];  // A: 2x16KB @0 | B: 2x16KB @32KB
  const int NT = K / 64;
  const int tid = threadIdx.x;
  const int lane = tid & 63, w = tid >> 6;
  const int g = lane >> 4, c16 = lane & 15;
  const int wm = (w >> 1) * 64, wn = (w & 1) * 64;

  const int wgid = blockIdx.y * gridDim.x + blockIdx.x;
  const int xcd = wgid & 7, pi = wgid >> 3;
  const int bxs = pi & 7;
  const int bys = 4 * xcd + (pi >> 3);
  const int brow = bys * 128, bcol = bxs * 128;

  const int lrow = lane >> 3;
  const int scol = ((lane & 7) ^ lrow) << 4;
  const int rswz = (c16 & 7) << 4;

  f32x4 acc[4][4];
#pragma unroll
  for (int m = 0; m < 4; ++m)
#pragma unroll
    for (int n = 0; n < 4; ++n) acc[m][n] = f32x4{0.f, 0.f, 0.f, 0.f};

  const size_t ldb = (size_t)K * 2;
  const char* Abase = (const char*)A + (size_t)brow * ldb;
  const char* Bbase = (const char*)Bt + (size_t)bcol * ldb;

  auto STAGE = [&](int kt) {
    const int par = kt & 1;
    char* Adst = smem_p + par * 16384;
    char* Bdst = smem_p + 32768 + par * 16384;
    const size_t koff = (size_t)kt * 128;
#pragma unroll
    for (int i = 0; i < 4; ++i) {
      const int c = w * 4 + i;
      const int row = c * 8 + lrow;
      async16(Abase + (size_t)row * ldb + koff + scol, Adst + c * 1024);
      async16(Bbase + (size_t)row * ldb + koff + scol, Bdst + c * 1024);
    }
  };

  STAGE(0);
  STAGE(1);

  for (int kt = 0; kt < NT; ++kt) {
    const int par = kt & 1;
    if (kt + 1 < NT)
      asm volatile("s_waitcnt vmcnt(8)" ::: "memory");
    else
      asm volatile("s_waitcnt vmcnt(0)" ::: "memory");
    __builtin_amdgcn_sched_barrier(0);
    __builtin_amdgcn_s_barrier();
    __builtin_amdgcn_sched_barrier(0);
    const char* Ap = smem_p + par * 16384;
    const char* Bp = smem_p + 32768 + par * 16384;
#pragma unroll
    for (int kc = 0; kc < 2; ++kc) {
      const int cb = (kc * 64 + g * 16) ^ rswz;
      u32x4 af[4], bf8[4];
#pragma unroll
      for (int m = 0; m < 4; ++m)
        af[m] = *(const u32x4*)(Ap + (wm + m * 16 + c16) * 128 + cb);
#pragma unroll
      for (int n = 0; n < 4; ++n)
        bf8[n] = *(const u32x4*)(Bp + (wn + n * 16 + c16) * 128 + cb);
#pragma unroll
      for (int m = 0; m < 4; ++m)
#pragma unroll
        for (int n = 0; n < 4; ++n) mfma16(acc[m][n], af[m], bf8[n]);
    }
    __builtin_amdgcn_sched_barrier(0);
    __builtin_amdgcn_s_barrier();
    __builtin_amdgcn_sched_barrier(0);
    if (kt + 2 < NT) STAGE(kt + 2);
  }

  float* Ef = (float*)smem_p;  // [64][128] f32 = 32KB
#pragma unroll
  for (int pass = 0; pass < 2; ++pass) {
    __syncthreads();
    if ((wm >> 6) == pass) {
#pragma unroll
      for (int n = 0; n < 4; ++n) {
        const float bv = bias[bcol + wn + n * 16 + c16];
#pragma unroll
        for (int m = 0; m < 4; ++m)
#pragma unroll
          for (int r = 0; r < 4; ++r)
            Ef[(m * 16 + g * 4 + r) * 128 + wn + n * 16 + c16] = acc[m][n][r] + bv;
      }
    }
    __syncthreads();
#pragma unroll
    for (int i = 0; i < 8; ++i) {
      const int chunk = tid + i * 256;
      const int row = chunk >> 5;
      const int c4 = (chunk & 31) * 4;
      f32x4 v4 = *(const f32x4*)&Ef[row * 128 + c4];
      *(f32x4*)&outF[(size_t)(brow + pass * 64 + row) * N + bcol + c4] = v4;
    }
  }
}

// ----------------------------------------------------------- attention ----
// R16-proven (42.0us, FETCH 12.4MB): R9 structure + XCD-bh-locality mapping.
__global__ __launch_bounds__(256) void attn_fwd(
    const u16* __restrict__ qw, const u16* __restrict__ kw,
    const u16* __restrict__ vw, u16* __restrict__ ao) {
  extern __shared__ u16 smem_a[];  // [4][64*64] K, then [4][64*64] V (64KB)
  const int tid = threadIdx.x;
  const int lane = tid & 63, w = tid >> 6;
  const int ql = lane & 31, half = lane >> 5;
  const int id = blockIdx.x;
  const int xcd = id & 7, slot = id >> 3;
  const int bhl = slot >> 4, qi = slot & 15;
  const int bh = (xcd << 2) + bhl;
  const int qb = (bhl & 2) ? (15 - qi) : qi;
  const int q0w = qb * 128 + w * 32;
  const int qg = q0w + ql;
  const int lrow = lane >> 3;
  const int scol = ((lane & 7) ^ lrow) << 4;
  const int rswz = (ql & 7) << 4;

  u32x4 qf[4];
  {
    const u16* qrow = qw + ((size_t)bh * TT + qg) * DD;
    const float qs = 0.125f * 1.44269504f;
#pragma unroll
    for (int dwin = 0; dwin < 4; ++dwin) {
      u16x8 u = *(const u16x8*)(qrow + dwin * 16 + half * 8);
      u16x8 s;
#pragma unroll
      for (int j = 0; j < 8; ++j) s[j] = f2bf(bf2f(u[j]) * qs);
      qf[dwin] = __builtin_bit_cast(u32x4, s);
    }
  }

  f32x16 o0, o1;
#pragma unroll
  for (int i = 0; i < 16; ++i) { o0[i] = 0.f; o1[i] = 0.f; }
  float l_run = 0.f;

  const char* kbase = (const char*)kw + ((size_t)bh * TT) * 128;
  const char* vbase = (const char*)vw + ((size_t)bh * DD) * (TT * 2);

  const int nt = 2 * qb + 2;  // always even

  auto kptr = [&](int b) { return (char*)(smem_a + (b & 3) * 4096); };
  auto vptr = [&](int b) { return (char*)(smem_a + 16384 + (b & 3) * 4096); };

  auto STAGE = [&](int kt_) {
    if (kt_ >= nt) return;
    const int t0_ = kt_ * 64;
#pragma unroll
    for (int i_ = 0; i_ < 2; ++i_) {
      const int chunk = w * 2 + i_;
      const int row = chunk * 8 + lrow;
      async16(kbase + (size_t)(t0_ + row) * 128 + scol, kptr(kt_) + chunk * 1024);
      async16(vbase + (size_t)row * (TT * 2) + (size_t)t0_ * 2 + scol,
              vptr(kt_) + chunk * 1024);
    }
  };

  auto QK = [&](int kt_, f32x16& sa, f32x16& sb) {
    const char* Kc = kptr(kt_);
#pragma unroll
    for (int i = 0; i < 16; ++i) { sa[i] = 0.f; sb[i] = 0.f; }
    __builtin_amdgcn_s_setprio(1);
#pragma unroll
    for (int dwin = 0; dwin < 4; ++dwin) {
      const int cb = (dwin * 32 + half * 16) ^ rswz;
      u32x4 ak0 = *(const u32x4*)(Kc + (0 + ql) * 128 + cb);
      u32x4 ak1 = *(const u32x4*)(Kc + (32 + ql) * 128 + cb);
      mfma32(sa, ak0, qf[dwin]);
      mfma32(sb, ak1, qf[dwin]);
    }
    __builtin_amdgcn_s_setprio(0);
  };

  auto FINISH = [&](int kt_, f32x16& s0, f32x16& s1) {
    const int t0 = kt_ * 64;
    if (t0 >= q0w + 32) return;
    if (t0 + 63 > q0w) {
      const int kb = t0 + 4 * half - qg;
#pragma unroll
      for (int r = 0; r < 16; ++r) {
        const int ko = (r & 3) + 8 * (r >> 2);
        if (kb + ko > 0) s0[r] = -1e30f;
        if (kb + 32 + ko > 0) s1[r] = -1e30f;
      }
    }
#pragma unroll
    for (int i = 0; i < 16; ++i) {
      s0[i] = exp2g(s0[i]);
      s1[i] = exp2g(s1[i]);
    }
    float a8[8];
#pragma unroll
    for (int i = 0; i < 8; ++i)
      a8[i] = (s0[i] + s0[i + 8]) + (s1[i] + s1[i + 8]);
    float rs = ((a8[0] + a8[1]) + (a8[2] + a8[3])) + ((a8[4] + a8[5]) + (a8[6] + a8[7]));
    rs += __shfl_xor(rs, 32, 64);
    l_run += rs;

    u32x4 pf[4];
#pragma unroll
    for (int win = 0; win < 4; ++win) {
      const int b = (win & 1) * 8;
      u32 w0, w1, w2, w3;
      if (win < 2) {
        w0 = cvtpk(s0[b + 0], s0[b + 1]); w2 = cvtpk(s0[b + 4], s0[b + 5]);
        w1 = cvtpk(s0[b + 2], s0[b + 3]); w3 = cvtpk(s0[b + 6], s0[b + 7]);
      } else {
        w0 = cvtpk(s1[b + 0], s1[b + 1]); w2 = cvtpk(s1[b + 4], s1[b + 5]);
        w1 = cvtpk(s1[b + 2], s1[b + 3]); w3 = cvtpk(s1[b + 6], s1[b + 7]);
      }
      pswap(w0, w2);
      pswap(w1, w3);
      pf[win] = u32x4{w0, w1, w2, w3};
    }
    const char* Vc = vptr(kt_);
    __builtin_amdgcn_s_setprio(1);
#pragma unroll
    for (int win = 0; win < 4; ++win) {
      const int cb = (win * 32 + half * 16) ^ rswz;
      u32x4 av0 = *(const u32x4*)(Vc + (0 + ql) * 128 + cb);
      u32x4 av1 = *(const u32x4*)(Vc + (32 + ql) * 128 + cb);
      mfma32(o0, av0, pf[win]);
      mfma32(o1, av1, pf[win]);
    }
    __builtin_amdgcn_s_setprio(0);
  };

  STAGE(0);
  STAGE(1);
  STAGE(2);
  if (nt >= 3)
    asm volatile("s_waitcnt vmcnt(8)" ::: "memory");
  else
    asm volatile("s_waitcnt vmcnt(4)" ::: "memory");
  __builtin_amdgcn_sched_barrier(0);
  __builtin_amdgcn_s_barrier();
  __builtin_amdgcn_sched_barrier(0);

  f32x16 sA0, sA1, sB0, sB1;
  QK(0, sA0, sA1);

#define BODY(KT, C0, C1, N0, N1)                                          \
  {                                                                       \
    const int kt_b = (KT);                                                \
    if (kt_b + 2 < nt)                                                    \
      asm volatile("s_waitcnt vmcnt(4)" ::: "memory");                    \
    else                                                                  \
      asm volatile("s_waitcnt vmcnt(0)" ::: "memory");                    \
    __builtin_amdgcn_sched_barrier(0);                                    \
    __builtin_amdgcn_s_barrier();                                         \
    __builtin_amdgcn_sched_barrier(0);                                    \
    STAGE(kt_b + 3);                                                      \
    if (kt_b + 1 < nt && (kt_b + 1) * 64 < q0w + 32) QK(kt_b + 1, N0, N1);\
    FINISH(kt_b, C0, C1);                                                 \
  }

  for (int kt2 = 0; kt2 < nt; kt2 += 2) {
    BODY(kt2, sA0, sA1, sB0, sB1);
    BODY(kt2 + 1, sB0, sB1, sA0, sA1);
  }
#undef BODY

  const int b = bh >> 4, h = bh & 15;
  const float inv = 1.f / l_run;
  u16* aorow = ao + ((size_t)(b * TT) + qg) * CC + h * DD;
#pragma unroll
  for (int rg = 0; rg < 4; ++rg) {
    u16x4 t0v, t1v;
#pragma unroll
    for (int j = 0; j < 4; ++j) {
      t0v[j] = f2bf(o0[rg * 4 + j] * inv);
      t1v[j] = f2bf(o1[rg * 4 + j] * inv);
    }
    *(u16x4*)(aorow + 8 * rg + 4 * half) = t0v;
    *(u16x4*)(aorow + 32 + 8 * rg + 4 * half) = t1v;
  }
}

// -------------------------------------------------------------- launch ----
extern "C" void kernel_launch(void* const* d_in, const int* in_sizes, int n_in,
                              void* d_out, int out_size, void* d_ws, size_t ws_size,
                              hipStream_t stream) {
  const float* x  = (const float*)d_in[0];
  const float* Wa = (const float*)d_in[1];
  const float* ba = (const float*)d_in[2];
  const float* Wp = (const float*)d_in[3];
  const float* bp = (const float*)d_in[4];
  float* out = (float*)d_out;

  char* ws = (char*)d_ws;
  const size_t MB = 1ull << 20;
  u16* x_bf = (u16*)(ws);            // 8 MB  [4096][1024]
  u16* ao   = (u16*)(ws);            // 8 MB  alias (x_bf dead after QKV GEMM)
  u16* Wa_t = (u16*)(ws + 8 * MB);   // 6 MB  [3072][1024]
  u16* Wp_t = (u16*)(ws + 14 * MB);  // 2 MB  [1024][1024]
  u16* q_ws = (u16*)(ws + 16 * MB);  // 8 MB  [32][2048][64]
  u16* k_ws = (u16*)(ws + 24 * MB);  // 8 MB  [32][2048][64]
  u16* v_ws = (u16*)(ws + 32 * MB);  // 8 MB  [32][64][2048]

  static bool attr_set = []() {
    hipFuncSetAttribute((const void*)gemm_qkv256,
                        hipFuncAttributeMaxDynamicSharedMemorySize, 114688);
    hipFuncSetAttribute((const void*)gemm_proj,
                        hipFuncAttributeMaxDynamicSharedMemorySize, 65536);
    hipFuncSetAttribute((const void*)attn_fwd,
                        hipFuncAttributeMaxDynamicSharedMemorySize, 65536);
    return true;
  }();
  (void)attr_set;

  hipLaunchKernelGGL(prep_all, dim3(160, 32), dim3(32, 32), 0, stream,
                     x, Wa, Wp, x_bf, Wa_t, Wp_t);
  hipLaunchKernelGGL(gemm_qkv256, dim3(256), dim3(512), 114688, stream,
                     x_bf, Wa_t, ba, q_ws, k_ws, v_ws);
  hipLaunchKernelGGL(attn_fwd, dim3(512), dim3(256), 65536, stream,
                     q_ws, k_ws, v_ws, ao);
  hipLaunchKernelGGL(gemm_proj, dim3(CC / 128, MDIM / 128), dim3(256), 65536, stream,
                     ao, Wp_t, bp, out, MDIM, CC, CC);
}